// Round 1
// baseline (504.095 us; speedup 1.0000x reference)
//
#include <hip/hip_runtime.h>
#include <stdint.h>

// Problem constants
#define NN   16
#define HH   112
#define WW   112
#define CIN  256
#define COUT 256
#define HP   114          // padded height
#define WP   114          // padded width
#define M_TOTAL (NN * HH * WW)                    // 200704
#define XP_BYTES ((size_t)NN * HP * WP * CIN)     // 53,231,616
#define WPK_BYTES ((size_t)9 * COUT * CIN)        // 589,824

typedef int v4i __attribute__((ext_vector_type(4)));

__device__ __forceinline__ void load_lds16(const void* g, void* l) {
  __builtin_amdgcn_global_load_lds(
      (const __attribute__((address_space(1))) void*)g,
      (__attribute__((address_space(3))) void*)l, 16, 0, 0);
}

// ---------------- pack x: int32 NHWC -> int8 padded [N][114][114][256] ----------------
__global__ void pack_x_kernel(const int* __restrict__ x, char* __restrict__ xp) {
  int t = blockIdx.x * 256 + threadIdx.x;   // exactly M_TOTAL*16 threads
  int g = t & 15;                           // 16-channel group
  int p = t >> 4;                           // pixel index
  int w = p % WW;
  int t2 = p / WW;
  int h = t2 % HH;
  int n = t2 / HH;
  const int* src = x + (size_t)p * CIN + g * 16;
  int4 i0 = ((const int4*)src)[0];
  int4 i1 = ((const int4*)src)[1];
  int4 i2 = ((const int4*)src)[2];
  int4 i3 = ((const int4*)src)[3];
  int vals[16] = {i0.x, i0.y, i0.z, i0.w, i1.x, i1.y, i1.z, i1.w,
                  i2.x, i2.y, i2.z, i2.w, i3.x, i3.y, i3.z, i3.w};
  int4 ov;
  char* pc = (char*)&ov;
#pragma unroll
  for (int i = 0; i < 16; i++) pc[i] = (char)vals[i];
  size_t dst = (((size_t)n * HP + (h + 1)) * WP + (w + 1)) * CIN + (size_t)g * 16;
  *(int4*)(xp + dst) = ov;
}

// zero the 1-pixel border of xp (borders = h in {0,113} full rows + w in {0,113})
__global__ void zero_border_kernel(char* __restrict__ xp) {
  int t = blockIdx.x * 256 + threadIdx.x;   // exactly 7232*16 threads
  int g = t & 15;
  int pix = t >> 4;                          // 0..7231
  int n = pix / 452;
  int b = pix % 452;
  int h, w;
  if (b < 114) { h = 0; w = b; }
  else if (b < 228) { h = 113; w = b - 114; }
  else { int r = b - 228; h = 1 + (r >> 1); w = (r & 1) ? 113 : 0; }
  size_t dst = (((size_t)n * HP + h) * WP + w) * CIN + (size_t)g * 16;
  *(int4*)(xp + dst) = make_int4(0, 0, 0, 0);
}

// ---------------- pack weight: OHWI int32 -> int8 [tap][cout][cin] ----------------
__global__ void pack_w_kernel(const int* __restrict__ wgt, char* __restrict__ wp) {
  int t = blockIdx.x * 256 + threadIdx.x;   // exactly 2304*16 threads
  int g = t & 15;
  int r = t >> 4;                            // 0..2303 = cout*9 + tap
  int tap = r % 9;
  int cout = r / 9;
  const int* src = wgt + ((size_t)(cout * 9 + tap)) * CIN + g * 16;
  int4 i0 = ((const int4*)src)[0];
  int4 i1 = ((const int4*)src)[1];
  int4 i2 = ((const int4*)src)[2];
  int4 i3 = ((const int4*)src)[3];
  int vals[16] = {i0.x, i0.y, i0.z, i0.w, i1.x, i1.y, i1.z, i1.w,
                  i2.x, i2.y, i2.z, i2.w, i3.x, i3.y, i3.z, i3.w};
  int4 ov;
  char* pc = (char*)&ov;
#pragma unroll
  for (int i = 0; i < 16; i++) pc[i] = (char)vals[i];
  size_t dst = ((size_t)tap * COUT + cout) * CIN + (size_t)g * 16;
  *(int4*)(wp + dst) = ov;
}

// ---------------- implicit-GEMM conv: C[M=200704][256] = A[M][2304] * B[2304][256] ----------------
// A[m][(tap,ci)] = xp[pixel(m) shifted by tap][ci]; B stored transposed as wp[tap][cout][ci].
// Tile: 128x128, BK=64 (one 16x16x64 MFMA K-step), 4 waves, each wave 64x64 = 4x4 MFMA tiles.
__global__ __launch_bounds__(256) void conv_mfma_kernel(const char* __restrict__ xp,
                                                        const char* __restrict__ wp,
                                                        int* __restrict__ out) {
  __shared__ __align__(16) char As[128 * 64];
  __shared__ __align__(16) char Bs[128 * 64];
  const int tid = threadIdx.x;
  const int lane = tid & 63;
  const int wave = tid >> 6;
  const int ntile = blockIdx.x & 1;
  const int mtile = blockIdx.x >> 1;

  // ---- staging addresses (per lane, 2 chunks of 16 rows each per wave) ----
  // LDS layout per tile: row-major [128 rows][4 cols of 16B], column XOR-swizzled:
  // position (row, c) holds global 16B-column (c ^ ((row>>1)&3)).
  const char* gA[2];
  const char* gB[2];
  char* lA[2];
  char* lB[2];
#pragma unroll
  for (int j = 0; j < 2; j++) {
    int c = wave * 2 + j;                 // chunk 0..7
    int row = c * 16 + (lane >> 2);       // tile row this lane stages
    int colg = (lane & 3) ^ ((row >> 1) & 3);
    // A: decompose m -> (n,h,w); xp is padded so (h+ky, w+kx) indexes directly
    int m = mtile * 128 + row;
    int w = m % WW;
    int t2 = m / WW;
    int h = t2 % HH;
    int n = t2 / HH;
    gA[j] = xp + (((size_t)n * HP + h) * WP + w) * CIN + (size_t)colg * 16;
    lA[j] = As + c * 1024;
    // B: rows are cout (contiguous ci) in wp[tap][cout][ci]
    int co = ntile * 128 + row;
    gB[j] = wp + (size_t)co * CIN + (size_t)colg * 16;
    lB[j] = Bs + c * 1024;
  }

  // ---- compute fragment LDS offsets ----
  const int wm = wave & 1;
  const int wn = wave >> 1;
  int aoff[4], boff[4];
#pragma unroll
  for (int i = 0; i < 4; i++) {
    int ra = wm * 64 + i * 16 + (lane & 15);
    aoff[i] = ra * 64 + (((lane >> 4) ^ ((ra >> 1) & 3)) * 16);
    int rb = wn * 64 + i * 16 + (lane & 15);
    boff[i] = rb * 64 + (((lane >> 4) ^ ((rb >> 1) & 3)) * 16);
  }

  v4i acc[4][4];
#pragma unroll
  for (int i = 0; i < 4; i++)
#pragma unroll
    for (int j = 0; j < 4; j++) acc[i][j] = (v4i){0, 0, 0, 0};

#pragma unroll 1
  for (int ks = 0; ks < 36; ks++) {
    const int tap = ks >> 2;
    const int kb = ks & 3;
    const int ky = tap / 3;
    const int kx = tap - ky * 3;
    const int offA = (ky * WP + kx) * CIN + kb * 64;
    const int offB = tap * (COUT * CIN) + kb * 64;
    __syncthreads();   // previous compute done reading LDS
    load_lds16(gA[0] + offA, lA[0]);
    load_lds16(gA[1] + offA, lA[1]);
    load_lds16(gB[0] + offB, lB[0]);
    load_lds16(gB[1] + offB, lB[1]);
    __syncthreads();   // staged data visible
    v4i af[4], bf[4];
#pragma unroll
    for (int i = 0; i < 4; i++) af[i] = *(const v4i*)(As + aoff[i]);
#pragma unroll
    for (int i = 0; i < 4; i++) bf[i] = *(const v4i*)(Bs + boff[i]);
#pragma unroll
    for (int i = 0; i < 4; i++)
#pragma unroll
      for (int j = 0; j < 4; j++)
        acc[i][j] = __builtin_amdgcn_mfma_i32_16x16x64_i8(af[i], bf[j], acc[i][j], 0, 0, 0);
  }

  // ---- epilogue: C/D layout col=lane&15, row=(lane>>4)*4+reg ----
#pragma unroll
  for (int i = 0; i < 4; i++) {
    const int mg = mtile * 128 + wm * 64 + i * 16 + ((lane >> 4) * 4);
#pragma unroll
    for (int r = 0; r < 4; r++) {
      int* orow = out + (size_t)(mg + r) * COUT + ntile * 128 + wn * 64 + (lane & 15);
#pragma unroll
      for (int j = 0; j < 4; j++) orow[j * 16] = acc[i][j][r];
    }
  }
}

// ---------------- fallback (only if ws too small): direct int32 conv ----------------
__global__ void conv_naive_kernel(const int* __restrict__ x, const int* __restrict__ wgt,
                                  int* __restrict__ out, int total) {
  int idx = blockIdx.x * 256 + threadIdx.x;
  if (idx >= total) return;
  int co = idx & 255;
  int p = idx >> 8;
  int w = p % WW;
  int t2 = p / WW;
  int h = t2 % HH;
  int n = t2 / HH;
  int acc = 0;
  for (int ky = 0; ky < 3; ky++) {
    int ih = h + ky - 1;
    if (ih < 0 || ih >= HH) continue;
    for (int kx = 0; kx < 3; kx++) {
      int iw = w + kx - 1;
      if (iw < 0 || iw >= WW) continue;
      const int* xs = x + (((size_t)n * HH + ih) * WW + iw) * CIN;
      const int* ws = wgt + ((size_t)co * 9 + ky * 3 + kx) * CIN;
      for (int ci = 0; ci < CIN; ci++) acc += xs[ci] * ws[ci];
    }
  }
  out[idx] = acc;
}

extern "C" void kernel_launch(void* const* d_in, const int* in_sizes, int n_in,
                              void* d_out, int out_size, void* d_ws, size_t ws_size,
                              hipStream_t stream) {
  const int* x = (const int*)d_in[0];
  const int* wgt = (const int*)d_in[1];
  int* out = (int*)d_out;
  const size_t need = XP_BYTES + WPK_BYTES;
  if (ws_size >= need) {
    char* xp = (char*)d_ws;
    char* wp = xp + XP_BYTES;
    pack_x_kernel<<<(M_TOTAL * 16) / 256, 256, 0, stream>>>(x, xp);       // 12544 blocks
    zero_border_kernel<<<(7232 * 16) / 256, 256, 0, stream>>>(xp);        // 452 blocks
    pack_w_kernel<<<(2304 * 16) / 256, 256, 0, stream>>>(wgt, wp);        // 144 blocks
    conv_mfma_kernel<<<(M_TOTAL / 128) * 2, 256, 0, stream>>>(xp, wp, out); // 3136 blocks
  } else {
    conv_naive_kernel<<<(out_size + 255) / 256, 256, 0, stream>>>(x, wgt, out, out_size);
  }
}

// Round 2
// 481.390 us; speedup vs baseline: 1.0472x; 1.0472x over previous
//
#include <hip/hip_runtime.h>
#include <stdint.h>

// Problem constants
#define NN   16
#define HH   112
#define WW   112
#define CIN  256
#define COUT 256
#define HP   114          // padded height
#define WP   114          // padded width
#define M_TOTAL (NN * HH * WW)                    // 200704
#define XP_BYTES ((size_t)NN * HP * WP * CIN)     // 53,231,616
#define WPK_BYTES ((size_t)9 * COUT * CIN)        // 589,824

typedef int v4i __attribute__((ext_vector_type(4)));

__device__ __forceinline__ void load_lds16(const void* g, void* l) {
  __builtin_amdgcn_global_load_lds(
      (const __attribute__((address_space(1))) void*)g,
      (__attribute__((address_space(3))) void*)l, 16, 0, 0);
}

// register-only byte pack: 4 ints (int8-valued) -> one dword
__device__ __forceinline__ int pack4(int a, int b, int c, int d) {
  return (a & 255) | ((b & 255) << 8) | ((c & 255) << 16) | (d << 24);
}

// ---------------- pack x: int32 NHWC -> int8 padded [N][114][114][256] ----------------
__global__ void pack_x_kernel(const int* __restrict__ x, char* __restrict__ xp) {
  int t = blockIdx.x * 256 + threadIdx.x;   // exactly M_TOTAL*16 threads
  int g = t & 15;                           // 16-channel group
  int p = t >> 4;                           // pixel index
  int w = p % WW;
  int t2 = p / WW;
  int h = t2 % HH;
  int n = t2 / HH;
  const int* src = x + (size_t)p * CIN + g * 16;
  int4 i0 = ((const int4*)src)[0];
  int4 i1 = ((const int4*)src)[1];
  int4 i2 = ((const int4*)src)[2];
  int4 i3 = ((const int4*)src)[3];
  int4 ov = make_int4(pack4(i0.x, i0.y, i0.z, i0.w),
                      pack4(i1.x, i1.y, i1.z, i1.w),
                      pack4(i2.x, i2.y, i2.z, i2.w),
                      pack4(i3.x, i3.y, i3.z, i3.w));
  size_t dst = (((size_t)n * HP + (h + 1)) * WP + (w + 1)) * CIN + (size_t)g * 16;
  *(int4*)(xp + dst) = ov;
}

// zero the 1-pixel border of xp (borders = h in {0,113} full rows + w in {0,113})
__global__ void zero_border_kernel(char* __restrict__ xp) {
  int t = blockIdx.x * 256 + threadIdx.x;   // exactly 7232*16 threads
  int g = t & 15;
  int pix = t >> 4;                          // 0..7231
  int n = pix / 452;
  int b = pix % 452;
  int h, w;
  if (b < 114) { h = 0; w = b; }
  else if (b < 228) { h = 113; w = b - 114; }
  else { int r = b - 228; h = 1 + (r >> 1); w = (r & 1) ? 113 : 0; }
  size_t dst = (((size_t)n * HP + h) * WP + w) * CIN + (size_t)g * 16;
  *(int4*)(xp + dst) = make_int4(0, 0, 0, 0);
}

// ---------------- pack weight: OHWI int32 -> int8 [tap][cout][cin] ----------------
__global__ void pack_w_kernel(const int* __restrict__ wgt, char* __restrict__ wp) {
  int t = blockIdx.x * 256 + threadIdx.x;   // exactly 2304*16 threads
  int g = t & 15;
  int r = t >> 4;                            // 0..2303 = cout*9 + tap
  int tap = r % 9;
  int cout = r / 9;
  const int* src = wgt + ((size_t)(cout * 9 + tap)) * CIN + g * 16;
  int4 i0 = ((const int4*)src)[0];
  int4 i1 = ((const int4*)src)[1];
  int4 i2 = ((const int4*)src)[2];
  int4 i3 = ((const int4*)src)[3];
  int4 ov = make_int4(pack4(i0.x, i0.y, i0.z, i0.w),
                      pack4(i1.x, i1.y, i1.z, i1.w),
                      pack4(i2.x, i2.y, i2.z, i2.w),
                      pack4(i3.x, i3.y, i3.z, i3.w));
  size_t dst = ((size_t)tap * COUT + cout) * CIN + (size_t)g * 16;
  *(int4*)(wp + dst) = ov;
}

// ---------------- implicit-GEMM conv: C[M=200704][256] = A[M][2304] * B[2304][256] ----------------
// A[m][(tap,ci)] = xp[pixel(m) shifted by tap][ci]; B stored as wp[tap][cout][ci].
// Tile: 128x256 (full COUT per block), BK=64, 4 waves in 2x2; each wave 64m x 128n
// = 4x8 MFMA 16x16x64 tiles. A staged once per block (was twice with 128x128).
__global__ __launch_bounds__(256, 2) void conv_mfma_kernel(const char* __restrict__ xp,
                                                           const char* __restrict__ wp,
                                                           int* __restrict__ out) {
  __shared__ __align__(16) char As[128 * 64];   // 8 KB
  __shared__ __align__(16) char Bs[256 * 64];   // 16 KB
  const int tid = threadIdx.x;
  const int lane = tid & 63;
  const int wave = tid >> 6;
  const int mtile = blockIdx.x;

  // ---- staging: 24 chunks of 1 KB (A: 0..7, B: 8..23); each wave stages 6 ----
  // LDS layout per tile: row-major [rows][4 cols of 16B], column XOR-swizzled:
  // position (row, c) holds global 16B-column (c ^ ((row>>1)&3)).
  const char* gptr[6];
  char* lptr[6];
  int  isA[6];
#pragma unroll
  for (int j = 0; j < 6; j++) {
    int c = wave * 6 + j;                 // chunk 0..23
    if (c < 8) {
      int row = c * 16 + (lane >> 2);     // A tile row
      int colg = (lane & 3) ^ ((row >> 1) & 3);
      int m = mtile * 128 + row;
      int w = m % WW;
      int t2 = m / WW;
      int h = t2 % HH;
      int n = t2 / HH;
      gptr[j] = xp + (((size_t)n * HP + h) * WP + w) * CIN + (size_t)colg * 16;
      lptr[j] = As + c * 1024;
      isA[j] = 1;
    } else {
      int cb = c - 8;
      int row = cb * 16 + (lane >> 2);    // B row = cout 0..255
      int colg = (lane & 3) ^ ((row >> 1) & 3);
      gptr[j] = wp + (size_t)row * CIN + (size_t)colg * 16;
      lptr[j] = Bs + cb * 1024;
      isA[j] = 0;
    }
  }

  // ---- compute fragment LDS offsets ----
  const int wm = wave & 1;   // m half (64 rows)
  const int wn = wave >> 1;  // n half (128 cols)
  int aoff[4], boff[8];
#pragma unroll
  for (int i = 0; i < 4; i++) {
    int ra = wm * 64 + i * 16 + (lane & 15);
    aoff[i] = ra * 64 + (((lane >> 4) ^ ((ra >> 1) & 3)) * 16);
  }
#pragma unroll
  for (int j = 0; j < 8; j++) {
    int rb = wn * 128 + j * 16 + (lane & 15);
    boff[j] = rb * 64 + (((lane >> 4) ^ ((rb >> 1) & 3)) * 16);
  }

  v4i acc[4][8];
#pragma unroll
  for (int i = 0; i < 4; i++)
#pragma unroll
    for (int j = 0; j < 8; j++) acc[i][j] = (v4i){0, 0, 0, 0};

#pragma unroll 1
  for (int ks = 0; ks < 36; ks++) {
    const int tap = ks >> 2;
    const int kb = ks & 3;
    const int ky = tap / 3;
    const int kx = tap - ky * 3;
    const int offA = (ky * WP + kx) * CIN + kb * 64;
    const int offB = tap * (COUT * CIN) + kb * 64;
    __syncthreads();   // previous compute done reading LDS
#pragma unroll
    for (int j = 0; j < 6; j++)
      load_lds16(gptr[j] + (isA[j] ? offA : offB), lptr[j]);
    __syncthreads();   // staged data visible
    v4i af[4], bf[8];
#pragma unroll
    for (int i = 0; i < 4; i++) af[i] = *(const v4i*)(As + aoff[i]);
#pragma unroll
    for (int j = 0; j < 8; j++) bf[j] = *(const v4i*)(Bs + boff[j]);
#pragma unroll
    for (int i = 0; i < 4; i++)
#pragma unroll
      for (int j = 0; j < 8; j++)
        acc[i][j] = __builtin_amdgcn_mfma_i32_16x16x64_i8(af[i], bf[j], acc[i][j], 0, 0, 0);
  }

  // ---- epilogue: C/D layout col=lane&15, row=(lane>>4)*4+reg ----
#pragma unroll
  for (int i = 0; i < 4; i++) {
    const int mg = mtile * 128 + wm * 64 + i * 16 + ((lane >> 4) * 4);
#pragma unroll
    for (int r = 0; r < 4; r++) {
      int* orow = out + (size_t)(mg + r) * COUT + wn * 128 + (lane & 15);
#pragma unroll
      for (int j = 0; j < 8; j++) orow[j * 16] = acc[i][j][r];
    }
  }
}

// ---------------- fallback (only if ws too small): direct int32 conv ----------------
__global__ void conv_naive_kernel(const int* __restrict__ x, const int* __restrict__ wgt,
                                  int* __restrict__ out, int total) {
  int idx = blockIdx.x * 256 + threadIdx.x;
  if (idx >= total) return;
  int co = idx & 255;
  int p = idx >> 8;
  int w = p % WW;
  int t2 = p / WW;
  int h = t2 % HH;
  int n = t2 / HH;
  int acc = 0;
  for (int ky = 0; ky < 3; ky++) {
    int ih = h + ky - 1;
    if (ih < 0 || ih >= HH) continue;
    for (int kx = 0; kx < 3; kx++) {
      int iw = w + kx - 1;
      if (iw < 0 || iw >= WW) continue;
      const int* xs = x + (((size_t)n * HH + ih) * WW + iw) * CIN;
      const int* ws = wgt + ((size_t)co * 9 + ky * 3 + kx) * CIN;
      for (int ci = 0; ci < CIN; ci++) acc += xs[ci] * ws[ci];
    }
  }
  out[idx] = acc;
}

extern "C" void kernel_launch(void* const* d_in, const int* in_sizes, int n_in,
                              void* d_out, int out_size, void* d_ws, size_t ws_size,
                              hipStream_t stream) {
  const int* x = (const int*)d_in[0];
  const int* wgt = (const int*)d_in[1];
  int* out = (int*)d_out;
  const size_t need = XP_BYTES + WPK_BYTES;
  if (ws_size >= need) {
    char* xp = (char*)d_ws;
    char* wp = xp + XP_BYTES;
    pack_x_kernel<<<(M_TOTAL * 16) / 256, 256, 0, stream>>>(x, xp);       // 12544 blocks
    zero_border_kernel<<<(7232 * 16) / 256, 256, 0, stream>>>(xp);        // 452 blocks
    pack_w_kernel<<<(2304 * 16) / 256, 256, 0, stream>>>(wgt, wp);        // 144 blocks
    conv_mfma_kernel<<<M_TOTAL / 128, 256, 0, stream>>>(xp, wp, out);     // 1568 blocks
  } else {
    conv_naive_kernel<<<(out_size + 255) / 256, 256, 0, stream>>>(x, wgt, out, out_size);
  }
}

// Round 3
// 460.734 us; speedup vs baseline: 1.0941x; 1.0448x over previous
//
#include <hip/hip_runtime.h>
#include <stdint.h>

// Problem constants
#define NN   16
#define HH   112
#define WW   112
#define CIN  256
#define COUT 256
#define HP   114          // padded height
#define WP   114          // padded width
#define M_TOTAL (NN * HH * WW)                    // 200704
#define XP_BYTES ((size_t)NN * HP * WP * CIN)     // 53,231,616
#define WPK_BYTES ((size_t)9 * COUT * CIN)        // 589,824

typedef int v4i __attribute__((ext_vector_type(4)));

__device__ __forceinline__ void load_lds16(const void* g, void* l) {
  __builtin_amdgcn_global_load_lds(
      (const __attribute__((address_space(1))) void*)g,
      (__attribute__((address_space(3))) void*)l, 16, 0, 0);
}

// register-only byte pack: 4 ints (int8-valued) -> one dword
__device__ __forceinline__ int pack4(int a, int b, int c, int d) {
  return (a & 255) | ((b & 255) << 8) | ((c & 255) << 16) | (d << 24);
}

// ---------------- pack x: int32 NHWC -> int8 padded [N][114][114][256] ----------------
// One thread per 4 consecutive ints: int4 read fully coalesced (16 B/lane contiguous),
// one packed dword out (256 B/wave contiguous).
__global__ void pack_x_kernel(const int* __restrict__ x, char* __restrict__ xp) {
  int t = blockIdx.x * 256 + threadIdx.x;   // exactly M_TOTAL*64 threads
  int c4 = t & 63;                          // dword index within pixel (4 ci each)
  int p = t >> 6;                           // pixel index
  int w = p % WW;
  int t2 = p / WW;
  int h = t2 % HH;
  int n = t2 / HH;
  int4 v = *(const int4*)(x + (size_t)t * 4);
  int ov = pack4(v.x, v.y, v.z, v.w);
  size_t dst = (((size_t)n * HP + (h + 1)) * WP + (w + 1)) * CIN + (size_t)c4 * 4;
  *(int*)(xp + dst) = ov;
}

// zero the 1-pixel border of xp (borders = h in {0,113} full rows + w in {0,113})
__global__ void zero_border_kernel(char* __restrict__ xp) {
  int t = blockIdx.x * 256 + threadIdx.x;   // exactly 7232*16 threads
  int g = t & 15;
  int pix = t >> 4;                          // 0..7231
  int n = pix / 452;
  int b = pix % 452;
  int h, w;
  if (b < 114) { h = 0; w = b; }
  else if (b < 228) { h = 113; w = b - 114; }
  else { int r = b - 228; h = 1 + (r >> 1); w = (r & 1) ? 113 : 0; }
  size_t dst = (((size_t)n * HP + h) * WP + w) * CIN + (size_t)g * 16;
  *(int4*)(xp + dst) = make_int4(0, 0, 0, 0);
}

// ---------------- pack weight: OHWI int32 -> int8 [tap][cout][cin] ----------------
__global__ void pack_w_kernel(const int* __restrict__ wgt, char* __restrict__ wp) {
  int t = blockIdx.x * 256 + threadIdx.x;   // exactly 2304*64 threads
  int c4 = t & 63;                           // dword within (tap,cout) row
  int r = t >> 6;                            // 0..2303 = cout*9 + tap
  int tap = r % 9;
  int cout = r / 9;
  int4 v = *(const int4*)(wgt + (size_t)t * 4);
  int ov = pack4(v.x, v.y, v.z, v.w);
  size_t dst = ((size_t)tap * COUT + cout) * CIN + (size_t)c4 * 4;
  *(int*)(wp + dst) = ov;
}

// ---------------- implicit-GEMM conv: C[M=200704][256] = A[M][2304] * B[2304][256] ----------------
// A[m][(tap,ci)] = xp[pixel(m) shifted by tap][ci]; B stored as wp[tap][cout][ci].
// Tile: 128x256 (full COUT per block), BK=64, 4 waves in 2x2; each wave 64m x 128n
// = 4x8 MFMA 16x16x64 tiles. Double-buffered LDS, ONE barrier per K-step:
//   top-of-step barrier (drains this wave's loads for step ks) -> issue loads for
//   ks+1 into the other buffer -> compute ks. Prefetch latency hides under compute.
__global__ __launch_bounds__(256, 2) void conv_mfma_kernel(const char* __restrict__ xp,
                                                           const char* __restrict__ wp,
                                                           int* __restrict__ out) {
  __shared__ __align__(16) char As[2 * 128 * 64];   // 16 KB (double buffer)
  __shared__ __align__(16) char Bs[2 * 256 * 64];   // 32 KB (double buffer)
  const int tid = threadIdx.x;
  const int lane = tid & 63;
  const int wave = tid >> 6;
  const int mtile = blockIdx.x;

  // ---- staging: 24 chunks of 1 KB (A: 0..7, B: 8..23); each wave stages 6 ----
  // LDS layout per tile: row-major [rows][4 cols of 16B], column XOR-swizzled:
  // position (row, c) holds global 16B-column (c ^ ((row>>1)&3)).
  const char* gptr[6];
  char* lptr[6];     // base within buffer 0
  int  isA[6];
#pragma unroll
  for (int j = 0; j < 6; j++) {
    int c = wave * 6 + j;                 // chunk 0..23
    if (c < 8) {
      int row = c * 16 + (lane >> 2);     // A tile row
      int colg = (lane & 3) ^ ((row >> 1) & 3);
      int m = mtile * 128 + row;
      int w = m % WW;
      int t2 = m / WW;
      int h = t2 % HH;
      int n = t2 / HH;
      gptr[j] = xp + (((size_t)n * HP + h) * WP + w) * CIN + (size_t)colg * 16;
      lptr[j] = As + c * 1024;
      isA[j] = 1;
    } else {
      int cb = c - 8;
      int row = cb * 16 + (lane >> 2);    // B row = cout 0..255
      int colg = (lane & 3) ^ ((row >> 1) & 3);
      gptr[j] = wp + (size_t)row * CIN + (size_t)colg * 16;
      lptr[j] = Bs + cb * 1024;
      isA[j] = 0;
    }
  }

  // ---- compute fragment LDS offsets (within buffer 0) ----
  const int wm = wave & 1;   // m half (64 rows)
  const int wn = wave >> 1;  // n half (128 cols)
  int aoff[4], boff[8];
#pragma unroll
  for (int i = 0; i < 4; i++) {
    int ra = wm * 64 + i * 16 + (lane & 15);
    aoff[i] = ra * 64 + (((lane >> 4) ^ ((ra >> 1) & 3)) * 16);
  }
#pragma unroll
  for (int j = 0; j < 8; j++) {
    int rb = wn * 128 + j * 16 + (lane & 15);
    boff[j] = rb * 64 + (((lane >> 4) ^ ((rb >> 1) & 3)) * 16);
  }

  v4i acc[4][8];
#pragma unroll
  for (int i = 0; i < 4; i++)
#pragma unroll
    for (int j = 0; j < 8; j++) acc[i][j] = (v4i){0, 0, 0, 0};

  // stage step ks into buffer b (b in {0,1}; A stride 8192, B stride 16384)
  auto stage = [&](int ks, int b) {
    int tap = ks >> 2;
    int kb = ks & 3;
    int ky = tap / 3;
    int kx = tap - ky * 3;
    int offA = (ky * WP + kx) * CIN + kb * 64;
    int offB = tap * (COUT * CIN) + kb * 64;
#pragma unroll
    for (int j = 0; j < 6; j++)
      load_lds16(gptr[j] + (isA[j] ? offA : offB),
                 lptr[j] + (isA[j] ? b * 8192 : b * 16384));
  };

  // prologue: loads for step 0 into buffer 0
  stage(0, 0);

#pragma unroll 1
  for (int ks = 0; ks < 36; ks++) {
    const int cur = ks & 1;
    __syncthreads();   // drains this wave's loads (step ks); syncs all waves.
                       // buf cur now valid; buf cur^1 readers finished last step.
    if (ks + 1 < 36) stage(ks + 1, cur ^ 1);
    const char* Ab = As + cur * 8192;
    const char* Bb = Bs + cur * 16384;
    v4i af[4], bf[8];
#pragma unroll
    for (int i = 0; i < 4; i++) af[i] = *(const v4i*)(Ab + aoff[i]);
#pragma unroll
    for (int j = 0; j < 8; j++) bf[j] = *(const v4i*)(Bb + boff[j]);
#pragma unroll
    for (int i = 0; i < 4; i++)
#pragma unroll
      for (int j = 0; j < 8; j++)
        acc[i][j] = __builtin_amdgcn_mfma_i32_16x16x64_i8(af[i], bf[j], acc[i][j], 0, 0, 0);
  }

  // ---- epilogue: C/D layout col=lane&15, row=(lane>>4)*4+reg ----
#pragma unroll
  for (int i = 0; i < 4; i++) {
    const int mg = mtile * 128 + wm * 64 + i * 16 + ((lane >> 4) * 4);
#pragma unroll
    for (int r = 0; r < 4; r++) {
      int* orow = out + (size_t)(mg + r) * COUT + wn * 128 + (lane & 15);
#pragma unroll
      for (int j = 0; j < 8; j++) orow[j * 16] = acc[i][j][r];
    }
  }
}

// ---------------- fallback (only if ws too small): direct int32 conv ----------------
__global__ void conv_naive_kernel(const int* __restrict__ x, const int* __restrict__ wgt,
                                  int* __restrict__ out, int total) {
  int idx = blockIdx.x * 256 + threadIdx.x;
  if (idx >= total) return;
  int co = idx & 255;
  int p = idx >> 8;
  int w = p % WW;
  int t2 = p / WW;
  int h = t2 % HH;
  int n = t2 / HH;
  int acc = 0;
  for (int ky = 0; ky < 3; ky++) {
    int ih = h + ky - 1;
    if (ih < 0 || ih >= HH) continue;
    for (int kx = 0; kx < 3; kx++) {
      int iw = w + kx - 1;
      if (iw < 0 || iw >= WW) continue;
      const int* xs = x + (((size_t)n * HH + ih) * WW + iw) * CIN;
      const int* ws = wgt + ((size_t)co * 9 + ky * 3 + kx) * CIN;
      for (int ci = 0; ci < CIN; ci++) acc += xs[ci] * ws[ci];
    }
  }
  out[idx] = acc;
}

extern "C" void kernel_launch(void* const* d_in, const int* in_sizes, int n_in,
                              void* d_out, int out_size, void* d_ws, size_t ws_size,
                              hipStream_t stream) {
  const int* x = (const int*)d_in[0];
  const int* wgt = (const int*)d_in[1];
  int* out = (int*)d_out;
  const size_t need = XP_BYTES + WPK_BYTES;
  if (ws_size >= need) {
    char* xp = (char*)d_ws;
    char* wp = xp + XP_BYTES;
    pack_x_kernel<<<(M_TOTAL * 64) / 256, 256, 0, stream>>>(x, xp);       // 50176 blocks
    zero_border_kernel<<<(7232 * 16) / 256, 256, 0, stream>>>(xp);        // 452 blocks
    pack_w_kernel<<<(2304 * 64) / 256, 256, 0, stream>>>(wgt, wp);        // 576 blocks
    conv_mfma_kernel<<<M_TOTAL / 128, 256, 0, stream>>>(xp, wp, out);     // 1568 blocks
  } else {
    conv_naive_kernel<<<(out_size + 255) / 256, 256, 0, stream>>>(x, wgt, out, out_size);
  }
}